// Round 2
// baseline (305.482 us; speedup 1.0000x reference)
//
#include <hip/hip_runtime.h>
#include <hip/hip_bf16.h>

// Problem constants
#define B_  16
#define S1_ 128
#define S2_ 256
#define H_  256
#define HM_ 512
#define QB  8   // q-rows per attn block

// ---------------------------------------------------------------------------
// proj: P[r][n] = sum_k X[r][k] * W[k][n] (+ bias[n])
// X: [R, 256], W: [256, 512] row-major slice of W1, P: [R, 512]
// 256 threads, tile 32 rows x 64 cols, thread tile 2x2? -> 2 rows x 4 cols.
// grid: (HM/64, R/32)  => 512 blocks (qp) / 1024 blocks (kp) = 2-4 blocks/CU.
// ---------------------------------------------------------------------------
__global__ __launch_bounds__(256) void proj_kernel(
    const float* __restrict__ X,
    const float* __restrict__ W,
    const float* __restrict__ bias,   // may be null
    float* __restrict__ P)
{
    const int tc = threadIdx.x & 15;   // col quad id  (0..15)
    const int tr = threadIdx.x >> 4;   // row pair id  (0..15)
    const int r0 = blockIdx.y * 32 + tr * 2;
    const int n0 = blockIdx.x * 64 + tc * 4;

    const float* x0 = X + (size_t)r0 * H_;
    const float* x1 = x0 + H_;
    const float* w0 = W + n0;

    float4 acc0 = make_float4(0.f, 0.f, 0.f, 0.f);
    float4 acc1 = make_float4(0.f, 0.f, 0.f, 0.f);

#pragma unroll 4
    for (int k = 0; k < H_; k += 4) {
        float4 xa = *(const float4*)(x0 + k);
        float4 xb = *(const float4*)(x1 + k);
        const float* xaf = (const float*)&xa;
        const float* xbf = (const float*)&xb;
#pragma unroll
        for (int j = 0; j < 4; ++j) {
            float4 wv = *(const float4*)(w0 + (size_t)(k + j) * HM_);
            float a = xaf[j], b = xbf[j];
            acc0.x = fmaf(a, wv.x, acc0.x); acc0.y = fmaf(a, wv.y, acc0.y);
            acc0.z = fmaf(a, wv.z, acc0.z); acc0.w = fmaf(a, wv.w, acc0.w);
            acc1.x = fmaf(b, wv.x, acc1.x); acc1.y = fmaf(b, wv.y, acc1.y);
            acc1.z = fmaf(b, wv.z, acc1.z); acc1.w = fmaf(b, wv.w, acc1.w);
        }
    }

    if (bias) {
        float4 bv = *(const float4*)(bias + n0);
        acc0.x += bv.x; acc0.y += bv.y; acc0.z += bv.z; acc0.w += bv.w;
        acc1.x += bv.x; acc1.y += bv.y; acc1.z += bv.z; acc1.w += bv.w;
    }
    *(float4*)(P + (size_t)r0       * HM_ + n0) = acc0;
    *(float4*)(P + (size_t)(r0 + 1) * HM_ + n0) = acc1;
}

// ---------------------------------------------------------------------------
// attn: block = (b, 8 q-rows), 512 threads: kt = t&255 (owns k-row),
// hb = t>>8 (owns h half [hb*256, hb*256+256)).
//  phase 1: kp chunk-staged in LDS (32 h per chunk, XOR-swizzled float4 slots,
//           double-buffered, loads issued early / LDS writes late),
//           qp & W2 read as wave-uniform global loads (scalar path).
//  phase 2: combine halves + masked exp (in place in Apart[0]).
//  phase 3: 64-wide shuffle row sums; PV with wave w owning q-row w,
//           64 lanes x float4 cover d=256 (coalesced value reads).
// ---------------------------------------------------------------------------
__global__ __launch_bounds__(512) void attn_kernel(
    const float* __restrict__ QP,     // [B*S1, HM]
    const float* __restrict__ KPB,    // [B*S2, HM] (b1 folded in)
    const float* __restrict__ value,  // [B, S2, H]
    const float* __restrict__ q_mask, // [B, S1]
    const float* __restrict__ k_mask, // [B, S2]
    const float* __restrict__ W2,     // [HM]
    const float* __restrict__ b2,     // [1]
    float* __restrict__ out)          // [B, S1, H]
{
    __shared__ float4 kp4[2][2][S2_][8];     // [buf][hb][row][slot] 128 KB
    __shared__ float  Apart[2][QB][S2_];     // 16 KB (Apart[0] reused as A)
    __shared__ float  km_s[S2_];
    __shared__ float  qm_s[QB];
    __shared__ float  rA_s[QB];

    const int t  = threadIdx.x;
    const int kt = t & 255;
    const int hb = t >> 8;

    // XCD-aware swizzle: XCD c handles 2 consecutive b's
    const int orig = blockIdx.x + (int)gridDim.x * blockIdx.y; // 0..255
    const int wg   = (orig & 7) * 32 + (orig >> 3);
    const int q0   = (wg & 15) * QB;
    const int b    = wg >> 4;

    // stage masks
    if (t < S2_)             km_s[t] = k_mask[b * S2_ + t];
    if (t >= 512 - QB)       qm_s[t - (512 - QB)] = q_mask[b * S1_ + q0 + (t - (512 - QB))];

    const float* qpb = QP + (size_t)(b * S1_ + q0) * HM_;  // wave-uniform reads
    const float* kpg = KPB + (size_t)(b * S2_) * HM_ + hb * (HM_ / 2);

    // staging geometry (fixed per thread): pass p covers rows p*32+(kt>>3)
    const int srow_lo = kt >> 3;        // 0..31
    const int scol    = kt & 7;         // float4 column within 32-h chunk
    const int swz     = scol ^ (srow_lo & 7);  // (p*32 row offset) & 7 == 0

    float4 stg[8];
    // prologue: load + write chunk 0 into buf 0
#pragma unroll
    for (int p = 0; p < 8; ++p)
        stg[p] = *(const float4*)(kpg + (size_t)(p * 32 + srow_lo) * HM_ + scol * 4);
#pragma unroll
    for (int p = 0; p < 8; ++p)
        kp4[0][hb][p * 32 + srow_lo][swz] = stg[p];

    float accs[QB];
#pragma unroll
    for (int q = 0; q < QB; ++q) accs[q] = 0.f;

    const int rswz = kt & 7;  // read-side row swizzle key

    for (int c = 0; c < 8; ++c) {
        __syncthreads();  // chunk c staged; buf (c+1)&1 free of readers
        const int buf = c & 1;
        // issue next chunk's global loads early
        if (c < 7) {
            const float* src = kpg + (c + 1) * 32;
#pragma unroll
            for (int p = 0; p < 8; ++p)
                stg[p] = *(const float4*)(src + (size_t)(p * 32 + srow_lo) * HM_ + scol * 4);
        }
        // compute chunk c
        const float* qpc = qpb + hb * (HM_ / 2) + c * 32;
        const float* w2c = W2 + hb * (HM_ / 2) + c * 32;
#pragma unroll
        for (int h4 = 0; h4 < 8; ++h4) {
            float4 kv = kp4[buf][hb][kt][h4 ^ rswz];
            float4 w4 = *(const float4*)(w2c + h4 * 4);   // uniform -> scalar
#pragma unroll
            for (int q = 0; q < QB; ++q) {
                float4 qv = *(const float4*)(qpc + q * HM_ + h4 * 4);  // uniform
                float s;
                s = qv.x + kv.x; s = s > 0.f ? s : 0.f; accs[q] = fmaf(s, w4.x, accs[q]);
                s = qv.y + kv.y; s = s > 0.f ? s : 0.f; accs[q] = fmaf(s, w4.y, accs[q]);
                s = qv.z + kv.z; s = s > 0.f ? s : 0.f; accs[q] = fmaf(s, w4.z, accs[q]);
                s = qv.w + kv.w; s = s > 0.f ? s : 0.f; accs[q] = fmaf(s, w4.w, accs[q]);
            }
        }
        // write next chunk to LDS (vmcnt wait lands here, after compute)
        if (c < 7) {
#pragma unroll
            for (int p = 0; p < 8; ++p)
                kp4[buf ^ 1][hb][p * 32 + srow_lo][swz] = stg[p];
        }
    }

    // write partial scores
#pragma unroll
    for (int q = 0; q < QB; ++q) Apart[hb][q][kt] = accs[q];
    __syncthreads();

    // combine halves + masked exp (in place into Apart[0] == A)
    {
        const float b2v = b2[0];
#pragma unroll
        for (int i = 0; i < 4; ++i) {
            const int idx = t + i * 512;
            const int q = idx >> 8, kk = idx & 255;
            float sc = Apart[0][q][kk] + Apart[1][q][kk] + b2v;
            float a  = (qm_s[q] * km_s[kk] == 0.f) ? 0.f : __expf(sc);
            Apart[0][q][kk] = a;
        }
    }
    __syncthreads();

    // row sums: wave w handles q-row w (8 waves == 8 q-rows)
    {
        const int q = t >> 6, lane = t & 63;
        float p = 0.f;
#pragma unroll
        for (int j = 0; j < 4; ++j) p += Apart[0][q][lane + 64 * j];
#pragma unroll
        for (int m = 32; m >= 1; m >>= 1) p += __shfl_xor(p, m, 64);
        if (lane == 0) rA_s[q] = 1.0f / fmaxf(p, 2e-15f);
    }
    __syncthreads();

    // PV: wave w owns q-row w; lanes cover d=256 as float4
    {
        const int w = t >> 6, lane = t & 63;
        const float4* vb = (const float4*)(value + (size_t)b * S2_ * H_);
        float4 o = make_float4(0.f, 0.f, 0.f, 0.f);
#pragma unroll 8
        for (int k = 0; k < S2_; ++k) {
            float  a = Apart[0][w][k];
            float4 v = vb[(size_t)k * (H_ / 4) + lane];
            o.x = fmaf(a, v.x, o.x); o.y = fmaf(a, v.y, o.y);
            o.z = fmaf(a, v.z, o.z); o.w = fmaf(a, v.w, o.w);
        }
        const float r = rA_s[w];
        o.x *= r; o.y *= r; o.z *= r; o.w *= r;
        *(float4*)(out + (size_t)(b * S1_ + q0 + w) * H_ + lane * 4) = o;
    }
}

extern "C" void kernel_launch(void* const* d_in, const int* in_sizes, int n_in,
                              void* d_out, int out_size, void* d_ws, size_t ws_size,
                              hipStream_t stream) {
    const float* query  = (const float*)d_in[0];  // [16,128,256]
    const float* key    = (const float*)d_in[1];  // [16,256,256]
    const float* value  = (const float*)d_in[2];  // [16,256,256]
    const float* q_mask = (const float*)d_in[3];  // [16,128]
    const float* k_mask = (const float*)d_in[4];  // [16,256]
    const float* W1     = (const float*)d_in[5];  // [512,512]
    const float* b1     = (const float*)d_in[6];  // [512]
    const float* W2     = (const float*)d_in[7];  // [512,1]
    const float* b2     = (const float*)d_in[8];  // [1]
    float*       out    = (float*)d_out;

    float* QP = (float*)d_ws;                          // [2048, 512] = 4 MB
    float* KP = (float*)d_ws + (size_t)B_ * S1_ * HM_; // [4096, 512] = 8 MB

    // qp = query @ W1[:256]
    proj_kernel<<<dim3(HM_ / 64, (B_ * S1_) / 32), 256, 0, stream>>>(
        query, W1, nullptr, QP);
    // kp = key @ W1[256:] + b1
    proj_kernel<<<dim3(HM_ / 64, (B_ * S2_) / 32), 256, 0, stream>>>(
        key, W1 + (size_t)H_ * HM_, b1, KP);

    attn_kernel<<<dim3(S1_ / QB, B_), 512, 0, stream>>>(
        QP, KP, value, q_mask, k_mask, W2, b2, out);
}

// Round 3
// 228.618 us; speedup vs baseline: 1.3362x; 1.3362x over previous
//
#include <hip/hip_runtime.h>
#include <hip/hip_bf16.h>

// Problem constants
#define B_  16
#define S1_ 128
#define S2_ 256
#define H_  256
#define HM_ 512
#define QB  4   // q-rows per attn block

// ---------------------------------------------------------------------------
// proj: P[r][n] = sum_k X[r][k] * W[k][n]   (natural layout, used for QP)
// X: [R, 256], W: [256, 512] row-major, P: [R, 512]
// 256 threads, tile 32 rows x 64 cols, thread tile 2 rows x 4 cols.
// grid: (HM/64, R/32) = (8, 64) = 512 blocks for QP.
// ---------------------------------------------------------------------------
__global__ __launch_bounds__(256) void proj_kernel(
    const float* __restrict__ X,
    const float* __restrict__ W,
    float* __restrict__ P)
{
    const int tc = threadIdx.x & 15;   // col quad id  (0..15)
    const int tr = threadIdx.x >> 4;   // row pair id  (0..15)
    const int r0 = blockIdx.y * 32 + tr * 2;
    const int n0 = blockIdx.x * 64 + tc * 4;

    const float* x0 = X + (size_t)r0 * H_;
    const float* x1 = x0 + H_;
    const float* w0 = W + n0;

    float4 acc0 = make_float4(0.f, 0.f, 0.f, 0.f);
    float4 acc1 = make_float4(0.f, 0.f, 0.f, 0.f);

#pragma unroll 4
    for (int k = 0; k < H_; k += 4) {
        float4 xa = *(const float4*)(x0 + k);
        float4 xb = *(const float4*)(x1 + k);
        const float* xaf = (const float*)&xa;
        const float* xbf = (const float*)&xb;
#pragma unroll
        for (int j = 0; j < 4; ++j) {
            float4 wv = *(const float4*)(w0 + (size_t)(k + j) * HM_);
            float a = xaf[j], b = xbf[j];
            acc0.x = fmaf(a, wv.x, acc0.x); acc0.y = fmaf(a, wv.y, acc0.y);
            acc0.z = fmaf(a, wv.z, acc0.z); acc0.w = fmaf(a, wv.w, acc0.w);
            acc1.x = fmaf(b, wv.x, acc1.x); acc1.y = fmaf(b, wv.y, acc1.y);
            acc1.z = fmaf(b, wv.z, acc1.z); acc1.w = fmaf(b, wv.w, acc1.w);
        }
    }
    *(float4*)(P + (size_t)r0       * HM_ + n0) = acc0;
    *(float4*)(P + (size_t)(r0 + 1) * HM_ + n0) = acc1;
}

// ---------------------------------------------------------------------------
// projT: PT[b][n][k2] = sum_d X[b*256+k2][d] * W[d][n] + bias[n]
// (KP stored transposed per batch so attn reads are coalesced along k)
// 256 threads, tile 32 n x 64 r, thread tile 2 n x 4 r.
// grid: (512/32, 4096/64) = (16, 64) = 1024 blocks.
// ---------------------------------------------------------------------------
__global__ __launch_bounds__(256) void projT_kernel(
    const float* __restrict__ X,     // [4096, 256]  (key)
    const float* __restrict__ W,     // [256, 512]   (W1[H:])
    const float* __restrict__ bias,  // [512]        (b1)
    float* __restrict__ PT)          // [16][512][256]
{
    const int rq = threadIdx.x & 15;   // r-quad id (0..15)
    const int np = threadIdx.x >> 4;   // n-pair id (0..15)
    const int r0 = blockIdx.y * 64 + rq * 4;
    const int n0 = blockIdx.x * 32 + np * 2;

    const float* x0 = X + (size_t)r0 * H_;

    // acc0 = column n0 over rows r0..r0+3 ; acc1 = column n0+1
    float4 acc0 = make_float4(0.f, 0.f, 0.f, 0.f);
    float4 acc1 = make_float4(0.f, 0.f, 0.f, 0.f);

#pragma unroll 4
    for (int d = 0; d < H_; d += 4) {
        float4 xr0 = *(const float4*)(x0 + 0 * H_ + d);
        float4 xr1 = *(const float4*)(x0 + 1 * H_ + d);
        float4 xr2 = *(const float4*)(x0 + 2 * H_ + d);
        float4 xr3 = *(const float4*)(x0 + 3 * H_ + d);
        const float* f0 = (const float*)&xr0;
        const float* f1 = (const float*)&xr1;
        const float* f2 = (const float*)&xr2;
        const float* f3 = (const float*)&xr3;
#pragma unroll
        for (int j = 0; j < 4; ++j) {
            float2 wv = *(const float2*)(W + (size_t)(d + j) * HM_ + n0);
            acc0.x = fmaf(f0[j], wv.x, acc0.x); acc1.x = fmaf(f0[j], wv.y, acc1.x);
            acc0.y = fmaf(f1[j], wv.x, acc0.y); acc1.y = fmaf(f1[j], wv.y, acc1.y);
            acc0.z = fmaf(f2[j], wv.x, acc0.z); acc1.z = fmaf(f2[j], wv.y, acc1.z);
            acc0.w = fmaf(f3[j], wv.x, acc0.w); acc1.w = fmaf(f3[j], wv.y, acc1.w);
        }
    }

    const float bv0 = bias[n0], bv1 = bias[n0 + 1];
    acc0.x += bv0; acc0.y += bv0; acc0.z += bv0; acc0.w += bv0;
    acc1.x += bv1; acc1.y += bv1; acc1.z += bv1; acc1.w += bv1;

    const int b = r0 >> 8;                 // 64-row tiles never straddle a batch
    float* base = PT + (size_t)b * HM_ * S2_ + (r0 & 255);
    *(float4*)(base + (size_t)n0       * S2_) = acc0;
    *(float4*)(base + (size_t)(n0 + 1) * S2_) = acc1;
}

// ---------------------------------------------------------------------------
// attn: block = (b, 4 q-rows), 512 threads: k = t&255 (owns k-col),
// hb = t>>8 (h half). kv loads are coalesced dwords from KPT; qp/W2 are
// LDS broadcasts. Partials combined in LDS; PV split-k over 8 waves.
// ---------------------------------------------------------------------------
__global__ __launch_bounds__(512, 4) void attn_kernel(
    const float* __restrict__ QP,     // [B*S1, HM]
    const float* __restrict__ KPT,    // [B][HM][S2] (b1 folded in)
    const float* __restrict__ value,  // [B, S2, H]
    const float* __restrict__ q_mask, // [B, S1]
    const float* __restrict__ k_mask, // [B, S2]
    const float* __restrict__ W2,     // [HM]
    const float* __restrict__ b2,     // [1]
    float* __restrict__ out)          // [B, S1, H]
{
    __shared__ __align__(16) float  qp_s[QB][HM_];     // 8 KB
    __shared__ __align__(16) float  w2_s[HM_];         // 2 KB
    __shared__ __align__(16) float  Ap[2][QB][S2_];    // 8 KB
    __shared__ __align__(16) float4 opart[2][QB][64];  // 8 KB
    __shared__ float rA_s[QB];
    __shared__ float qm_s[QB];
    __shared__ float km_s[S2_];

    const int t  = threadIdx.x;
    const int k  = t & 255;
    const int hb = t >> 8;

    // XCD-aware swizzle: 512 blocks, XCD x gets wg [x*64, x*64+64) = 2 b's
    const int orig = blockIdx.x + (int)gridDim.x * blockIdx.y;  // 0..511
    const int wg   = (orig & 7) * 64 + (orig >> 3);
    const int q0   = (wg & 31) * QB;
    const int b    = wg >> 5;

    // stage qp rows (4x512 floats = 512 float4), w2, masks
    {
        const float4* src = (const float4*)(QP + (size_t)(b * S1_ + q0) * HM_);
        ((float4*)&qp_s[0][0])[t] = src[t];
        if (t < HM_ / 4) ((float4*)w2_s)[t] = ((const float4*)W2)[t];
        if (t < S2_)     km_s[t] = k_mask[b * S2_ + t];
        if (t < QB)      qm_s[t] = q_mask[b * S1_ + q0 + t];
    }
    __syncthreads();

    // phase 1: scores partials over this thread's h half
    float accs[QB] = {0.f, 0.f, 0.f, 0.f};
    const float* kp = KPT + (size_t)b * HM_ * S2_ + (size_t)hb * (HM_ / 2) * S2_ + k;

#pragma unroll 2
    for (int h = 0; h < HM_ / 2; h += 4) {
        float kv0 = kp[(size_t)(h + 0) * S2_];
        float kv1 = kp[(size_t)(h + 1) * S2_];
        float kv2 = kp[(size_t)(h + 2) * S2_];
        float kv3 = kp[(size_t)(h + 3) * S2_];
        const int hoff = hb * (HM_ / 2) + h;
        float4 w4 = *(const float4*)&w2_s[hoff];
#pragma unroll
        for (int q = 0; q < QB; ++q) {
            float4 qv = *(const float4*)&qp_s[q][hoff];
            float s;
            s = qv.x + kv0; s = s > 0.f ? s : 0.f; accs[q] = fmaf(s, w4.x, accs[q]);
            s = qv.y + kv1; s = s > 0.f ? s : 0.f; accs[q] = fmaf(s, w4.y, accs[q]);
            s = qv.z + kv2; s = s > 0.f ? s : 0.f; accs[q] = fmaf(s, w4.z, accs[q]);
            s = qv.w + kv3; s = s > 0.f ? s : 0.f; accs[q] = fmaf(s, w4.w, accs[q]);
        }
    }
#pragma unroll
    for (int q = 0; q < QB; ++q) Ap[hb][q][k] = accs[q];
    __syncthreads();

    // phase 2: combine halves, mask, exp (in place into Ap[0])
    {
        const float b2v = b2[0];
#pragma unroll
        for (int i = 0; i < 2; ++i) {
            const int idx = t + i * 512;           // 0..1023
            const int q = idx >> 8, kk = idx & 255;
            float sc = Ap[0][q][kk] + Ap[1][q][kk] + b2v;
            Ap[0][q][kk] = (qm_s[q] * km_s[kk] == 0.f) ? 0.f : __expf(sc);
        }
    }
    __syncthreads();

    // row sums: waves 0..3 (one per q-row), 64-lane butterfly
    if (t < QB * 64) {
        const int q = t >> 6, lane = t & 63;
        float p = Ap[0][q][lane] + Ap[0][q][lane + 64] +
                  Ap[0][q][lane + 128] + Ap[0][q][lane + 192];
#pragma unroll
        for (int m = 32; m >= 1; m >>= 1) p += __shfl_xor(p, m, 64);
        if (lane == 0) rA_s[q] = 1.0f / fmaxf(p, 2e-15f);
    }
    __syncthreads();

    // PV: 8 waves = (q 0..3) x (k-half 0..1); lanes cover d=256 as float4
    {
        const int w = t >> 6, lane = t & 63;
        const int q = w & 3, kh = w >> 2;
        const float4* vb = (const float4*)(value + (size_t)b * S2_ * H_)
                           + (size_t)kh * 128 * (H_ / 4) + lane;
        const float* arow = &Ap[0][q][kh * 128];
        float4 o = make_float4(0.f, 0.f, 0.f, 0.f);
#pragma unroll 4
        for (int kk = 0; kk < 128; ++kk) {
            float  a = arow[kk];
            float4 v = vb[(size_t)kk * (H_ / 4)];
            o.x = fmaf(a, v.x, o.x); o.y = fmaf(a, v.y, o.y);
            o.z = fmaf(a, v.z, o.z); o.w = fmaf(a, v.w, o.w);
        }
        opart[kh][q][lane] = o;
    }
    __syncthreads();

    if (t < QB * 64) {
        const int q = t >> 6, lane = t & 63;
        float4 o0 = opart[0][q][lane];
        float4 o1 = opart[1][q][lane];
        const float r = rA_s[q];
        float4 res = make_float4((o0.x + o1.x) * r, (o0.y + o1.y) * r,
                                 (o0.z + o1.z) * r, (o0.w + o1.w) * r);
        *(float4*)(out + (size_t)(b * S1_ + q0 + q) * H_ + lane * 4) = res;
    }
}

extern "C" void kernel_launch(void* const* d_in, const int* in_sizes, int n_in,
                              void* d_out, int out_size, void* d_ws, size_t ws_size,
                              hipStream_t stream) {
    const float* query  = (const float*)d_in[0];  // [16,128,256]
    const float* key    = (const float*)d_in[1];  // [16,256,256]
    const float* value  = (const float*)d_in[2];  // [16,256,256]
    const float* q_mask = (const float*)d_in[3];  // [16,128]
    const float* k_mask = (const float*)d_in[4];  // [16,256]
    const float* W1     = (const float*)d_in[5];  // [512,512]
    const float* b1     = (const float*)d_in[6];  // [512]
    const float* W2     = (const float*)d_in[7];  // [512,1]
    const float* b2     = (const float*)d_in[8];  // [1]
    float*       out    = (float*)d_out;

    float* QP  = (float*)d_ws;                          // [2048, 512] = 4 MB
    float* KPT = (float*)d_ws + (size_t)B_ * S1_ * HM_; // [16][512][256] = 8 MB

    // qp = query @ W1[:256]   (natural layout)
    proj_kernel<<<dim3(HM_ / 64, (B_ * S1_) / 32), 256, 0, stream>>>(
        query, W1, QP);
    // kpT[b][h][k] = (key @ W1[256:] + b1) transposed per batch
    projT_kernel<<<dim3(HM_ / 32, (B_ * S2_) / 64), 256, 0, stream>>>(
        key, W1 + (size_t)H_ * HM_, b1, KPT);

    attn_kernel<<<dim3(S1_ / QB, B_), 512, 0, stream>>>(
        QP, KPT, value, q_mask, k_mask, W2, b2, out);
}

// Round 4
// 88.017 us; speedup vs baseline: 3.4707x; 2.5974x over previous
//
#include <hip/hip_runtime.h>
#include <hip/hip_bf16.h>

// Problem constants
#define B_  16
#define S1_ 128
#define S2_ 256
#define H_  256
#define HM_ 512
#define QB  4   // q-rows per attn block

// ---------------------------------------------------------------------------
// proj_kernel<MODE>: C = X @ W (+bias), X:[M,256] row-major, W rows 256,
// N=512. 64x64 tile, 256 threads, 4x4 per thread, BK=32 (8 steps).
// A-tile staged transposed in LDS (As[kk][m]); W-frags straight from global.
// MODE 0: natural store P[m][n]            (QP, no bias)
// MODE 1: store PT4[b][n/4][m&255][n&3] + bias  (KPT4 layout for attn)
// grid: 1-D, (M/64)*8 blocks.
// ---------------------------------------------------------------------------
template<int MODE>
__global__ __launch_bounds__(256, 2) void proj_kernel(
    const float* __restrict__ X,
    const float* __restrict__ W,
    const float* __restrict__ bias,
    float* __restrict__ P)
{
    __shared__ float As[32][68];   // [kk][m], padded

    const int t     = threadIdx.x;
    const int bid   = blockIdx.x;
    const int ntile = bid & 7;
    const int mtile = bid >> 3;
    const int m0    = mtile * 64;
    const int n0    = ntile * 64;

    // thread-tile coordinates (mode-dependent so stores coalesce)
    const int mq = MODE ? (t & 15) : (t >> 4);
    const int nq = MODE ? (t >> 4) : (t & 15);

    // staging coordinates
    const int cs = t & 7;    // k-quad within 32-wide K-slab
    const int rs = t >> 3;   // m-row (0..31), two passes 32 apart

    const float* xs0 = X + (size_t)(m0 + rs) * H_ + cs * 4;
    const float* xs1 = xs0 + (size_t)32 * H_;

    float4 xv0 = *(const float4*)xs0;
    float4 xv1 = *(const float4*)xs1;

    float4 acc[4];
#pragma unroll
    for (int i = 0; i < 4; ++i) acc[i] = make_float4(0.f, 0.f, 0.f, 0.f);

    const float* wbase = W + n0 + nq * 4;

    for (int step = 0; step < 8; ++step) {
        if (step > 0) __syncthreads();   // readers of previous tile done
        As[cs * 4 + 0][rs] = xv0.x;
        As[cs * 4 + 1][rs] = xv0.y;
        As[cs * 4 + 2][rs] = xv0.z;
        As[cs * 4 + 3][rs] = xv0.w;
        As[cs * 4 + 0][rs + 32] = xv1.x;
        As[cs * 4 + 1][rs + 32] = xv1.y;
        As[cs * 4 + 2][rs + 32] = xv1.z;
        As[cs * 4 + 3][rs + 32] = xv1.w;
        __syncthreads();

        if (step < 7) {   // prefetch next K-slab
            xv0 = *(const float4*)(xs0 + (step + 1) * 32);
            xv1 = *(const float4*)(xs1 + (step + 1) * 32);
        }

        const float* wrow = wbase + (size_t)(step * 32) * HM_;
#pragma unroll 8
        for (int kk = 0; kk < 32; ++kk) {
            float4 a4 = *(const float4*)&As[kk][mq * 4];
            float4 bf = *(const float4*)(wrow + (size_t)kk * HM_);
            float s0, s1, s2, s3;
            float4 v;
            if (MODE == 0) { s0 = a4.x; s1 = a4.y; s2 = a4.z; s3 = a4.w; v = bf; }
            else           { s0 = bf.x; s1 = bf.y; s2 = bf.z; s3 = bf.w; v = a4; }
            acc[0].x = fmaf(s0, v.x, acc[0].x); acc[0].y = fmaf(s0, v.y, acc[0].y);
            acc[0].z = fmaf(s0, v.z, acc[0].z); acc[0].w = fmaf(s0, v.w, acc[0].w);
            acc[1].x = fmaf(s1, v.x, acc[1].x); acc[1].y = fmaf(s1, v.y, acc[1].y);
            acc[1].z = fmaf(s1, v.z, acc[1].z); acc[1].w = fmaf(s1, v.w, acc[1].w);
            acc[2].x = fmaf(s2, v.x, acc[2].x); acc[2].y = fmaf(s2, v.y, acc[2].y);
            acc[2].z = fmaf(s2, v.z, acc[2].z); acc[2].w = fmaf(s2, v.w, acc[2].w);
            acc[3].x = fmaf(s3, v.x, acc[3].x); acc[3].y = fmaf(s3, v.y, acc[3].y);
            acc[3].z = fmaf(s3, v.z, acc[3].z); acc[3].w = fmaf(s3, v.w, acc[3].w);
        }
    }

    if (MODE == 0) {
        // acc[i] = C[m0+mq*4+i][n0+nq*4 .. +3]
#pragma unroll
        for (int i = 0; i < 4; ++i)
            *(float4*)(P + (size_t)(m0 + mq * 4 + i) * HM_ + n0 + nq * 4) = acc[i];
    } else {
        // acc[j] = C[m0+mq*4 .. +3][n0+nq*4+j]; add bias, transpose, store
        float4 b4 = *(const float4*)(bias + n0 + nq * 4);
        acc[0].x += b4.x; acc[0].y += b4.x; acc[0].z += b4.x; acc[0].w += b4.x;
        acc[1].x += b4.y; acc[1].y += b4.y; acc[1].z += b4.y; acc[1].w += b4.y;
        acc[2].x += b4.z; acc[2].y += b4.z; acc[2].z += b4.z; acc[2].w += b4.z;
        acc[3].x += b4.w; acc[3].y += b4.w; acc[3].z += b4.w; acc[3].w += b4.w;
        float4 tr[4];
        tr[0] = make_float4(acc[0].x, acc[1].x, acc[2].x, acc[3].x);
        tr[1] = make_float4(acc[0].y, acc[1].y, acc[2].y, acc[3].y);
        tr[2] = make_float4(acc[0].z, acc[1].z, acc[2].z, acc[3].z);
        tr[3] = make_float4(acc[0].w, acc[1].w, acc[2].w, acc[3].w);
        // PT4 float index: (((b*128 + n/4) * 256) + k_local) * 4 + (n&3)
        const int bb   = m0 >> 8;
        const int h4   = (n0 >> 2) + nq;       // n/4 group
        const int mloc = (m0 & 255) + mq * 4;
        float* dst = P + (((size_t)bb * 128 + h4) * 256 + mloc) * 4;
#pragma unroll
        for (int x = 0; x < 4; ++x)
            *(float4*)(dst + 4 * x) = tr[x];
    }
}

// ---------------------------------------------------------------------------
// attn: block = (b, 4 q-rows), 512 threads: k = t&255 (owns k-col),
// hb = t>>8 (h half). kv loads are coalesced b128 from KPT4; qp/W2 are
// LDS broadcasts. Partials combined in LDS; PV split-k over 8 waves.
// ---------------------------------------------------------------------------
__global__ __launch_bounds__(512, 4) void attn_kernel(
    const float* __restrict__ QP,     // [B*S1, HM]
    const float* __restrict__ KPT,    // [B][HM/4][S2][4] (b1 folded in)
    const float* __restrict__ value,  // [B, S2, H]
    const float* __restrict__ q_mask, // [B, S1]
    const float* __restrict__ k_mask, // [B, S2]
    const float* __restrict__ W2,     // [HM]
    const float* __restrict__ b2,     // [1]
    float* __restrict__ out)          // [B, S1, H]
{
    __shared__ __align__(16) float  qp_s[QB][HM_];     // 8 KB
    __shared__ __align__(16) float  w2_s[HM_];         // 2 KB
    __shared__ __align__(16) float  Ap[2][QB][S2_];    // 8 KB
    __shared__ __align__(16) float4 opart[2][QB][64];  // 8 KB
    __shared__ float rA_s[QB];
    __shared__ float qm_s[QB];
    __shared__ float km_s[S2_];

    const int t  = threadIdx.x;
    const int k  = t & 255;
    const int hb = t >> 8;

    // XCD-aware swizzle: 512 blocks, XCD x gets wg [x*64, x*64+64) = 2 b's
    const int orig = blockIdx.x + (int)gridDim.x * blockIdx.y;  // 0..511
    const int wg   = (orig & 7) * 64 + (orig >> 3);
    const int q0   = (wg & 31) * QB;
    const int b    = wg >> 5;

    // stage qp rows (4x512 floats = 512 float4), w2, masks
    {
        const float4* src = (const float4*)(QP + (size_t)(b * S1_ + q0) * HM_);
        ((float4*)&qp_s[0][0])[t] = src[t];
        if (t < HM_ / 4) ((float4*)w2_s)[t] = ((const float4*)W2)[t];
        if (t < S2_)     km_s[t] = k_mask[b * S2_ + t];
        if (t < QB)      qm_s[t] = q_mask[b * S1_ + q0 + t];
    }
    __syncthreads();

    // phase 1: score partials over this thread's h half (64 h-quads)
    float accs[QB] = {0.f, 0.f, 0.f, 0.f};
    const float4* kp4 = (const float4*)KPT + ((size_t)b * 128 + hb * 64) * S2_ + k;

#pragma unroll 2
    for (int h4 = 0; h4 < 64; ++h4) {
        float4 kv = kp4[(size_t)h4 * S2_];
        const int hoff = hb * (HM_ / 2) + h4 * 4;
        float4 w4 = *(const float4*)&w2_s[hoff];
#pragma unroll
        for (int q = 0; q < QB; ++q) {
            float4 qv = *(const float4*)&qp_s[q][hoff];
            float s;
            s = qv.x + kv.x; s = s > 0.f ? s : 0.f; accs[q] = fmaf(s, w4.x, accs[q]);
            s = qv.y + kv.y; s = s > 0.f ? s : 0.f; accs[q] = fmaf(s, w4.y, accs[q]);
            s = qv.z + kv.z; s = s > 0.f ? s : 0.f; accs[q] = fmaf(s, w4.z, accs[q]);
            s = qv.w + kv.w; s = s > 0.f ? s : 0.f; accs[q] = fmaf(s, w4.w, accs[q]);
        }
    }
#pragma unroll
    for (int q = 0; q < QB; ++q) Ap[hb][q][k] = accs[q];
    __syncthreads();

    // phase 2: combine halves, mask, exp (in place into Ap[0])
    {
        const float b2v = b2[0];
#pragma unroll
        for (int i = 0; i < 2; ++i) {
            const int idx = t + i * 512;           // 0..1023
            const int q = idx >> 8, kk = idx & 255;
            float sc = Ap[0][q][kk] + Ap[1][q][kk] + b2v;
            Ap[0][q][kk] = (qm_s[q] * km_s[kk] == 0.f) ? 0.f : __expf(sc);
        }
    }
    __syncthreads();

    // row sums: waves 0..3 (one per q-row), 64-lane butterfly
    if (t < QB * 64) {
        const int q = t >> 6, lane = t & 63;
        float p = Ap[0][q][lane] + Ap[0][q][lane + 64] +
                  Ap[0][q][lane + 128] + Ap[0][q][lane + 192];
#pragma unroll
        for (int m = 32; m >= 1; m >>= 1) p += __shfl_xor(p, m, 64);
        if (lane == 0) rA_s[q] = 1.0f / fmaxf(p, 2e-15f);
    }
    __syncthreads();

    // PV: 8 waves = (q 0..3) x (k-half 0..1); lanes cover d=256 as float4
    {
        const int w = t >> 6, lane = t & 63;
        const int q = w & 3, kh = w >> 2;
        const float4* vb = (const float4*)(value + (size_t)b * S2_ * H_)
                           + (size_t)kh * 128 * (H_ / 4) + lane;
        const float* arow = &Ap[0][q][kh * 128];
        float4 o = make_float4(0.f, 0.f, 0.f, 0.f);
#pragma unroll 4
        for (int kk = 0; kk < 128; ++kk) {
            float  a = arow[kk];
            float4 v = vb[(size_t)kk * (H_ / 4)];
            o.x = fmaf(a, v.x, o.x); o.y = fmaf(a, v.y, o.y);
            o.z = fmaf(a, v.z, o.z); o.w = fmaf(a, v.w, o.w);
        }
        opart[kh][q][lane] = o;
    }
    __syncthreads();

    if (t < QB * 64) {
        const int q = t >> 6, lane = t & 63;
        float4 o0 = opart[0][q][lane];
        float4 o1 = opart[1][q][lane];
        const float r = rA_s[q];
        float4 res = make_float4((o0.x + o1.x) * r, (o0.y + o1.y) * r,
                                 (o0.z + o1.z) * r, (o0.w + o1.w) * r);
        *(float4*)(out + (size_t)(b * S1_ + q0 + q) * H_ + lane * 4) = res;
    }
}

extern "C" void kernel_launch(void* const* d_in, const int* in_sizes, int n_in,
                              void* d_out, int out_size, void* d_ws, size_t ws_size,
                              hipStream_t stream) {
    const float* query  = (const float*)d_in[0];  // [16,128,256]
    const float* key    = (const float*)d_in[1];  // [16,256,256]
    const float* value  = (const float*)d_in[2];  // [16,256,256]
    const float* q_mask = (const float*)d_in[3];  // [16,128]
    const float* k_mask = (const float*)d_in[4];  // [16,256]
    const float* W1     = (const float*)d_in[5];  // [512,512]
    const float* b1     = (const float*)d_in[6];  // [512]
    const float* W2     = (const float*)d_in[7];  // [512,1]
    const float* b2     = (const float*)d_in[8];  // [1]
    float*       out    = (float*)d_out;

    float* QP   = (float*)d_ws;                          // [2048,512] = 4 MB
    float* KPT4 = (float*)d_ws + (size_t)B_ * S1_ * HM_; // [16][128][256][4] = 8 MB

    // qp = query @ W1[:256]  (natural layout)      M=2048 -> 32*8 = 256 blocks
    proj_kernel<0><<<256, 256, 0, stream>>>(query, W1, nullptr, QP);
    // kpT4 = (key @ W1[256:] + b1), [b][h/4][k][4]  M=4096 -> 64*8 = 512 blocks
    proj_kernel<1><<<512, 256, 0, stream>>>(key, W1 + (size_t)H_ * HM_, b1, KPT4);

    attn_kernel<<<dim3(S1_ / QB, B_), 512, 0, stream>>>(
        QP, KPT4, value, q_mask, k_mask, W2, b2, out);
}

// Round 5
// 83.469 us; speedup vs baseline: 3.6598x; 1.0545x over previous
//
#include <hip/hip_runtime.h>
#include <hip/hip_bf16.h>

// Problem constants
#define B_  16
#define S1_ 128
#define S2_ 256
#define H_  256
#define HM_ 512
#define QB  4   // q-rows per attn block

typedef _Float16 hf2 __attribute__((ext_vector_type(2)));
typedef _Float16 hf4 __attribute__((ext_vector_type(4)));

static __device__ inline hf2 u2h(unsigned u) {
    union { unsigned u; hf2 h; } x; x.u = u; return x.h;
}

static __device__ inline float dot2(hf2 a, hf2 b, float c) {
#if __has_builtin(__builtin_amdgcn_fdot2)
    return __builtin_amdgcn_fdot2(a, b, c, false);
#else
    asm("v_dot2_f32_f16 %0, %1, %2, %0" : "+v"(c) : "v"(a), "v"(b));
    return c;
#endif
}

// ---------------------------------------------------------------------------
// proj_all: one launch, 768 blocks.
//   blocks [0,256):   QPh  = fp16( query @ W1[:256] )            [2048][512]
//   blocks [256,768): KPTh = fp16( key @ W1[256:] + b1 ) in [b][h/8][k][8]
// 64x64 tile, 256 threads, 4x4 per thread, BK=32 (8 steps), fp32 math.
// ---------------------------------------------------------------------------
__global__ __launch_bounds__(256, 3) void proj_all_kernel(
    const float* __restrict__ query,
    const float* __restrict__ key,
    const float* __restrict__ W1,
    const float* __restrict__ b1,
    _Float16* __restrict__ QPh,
    _Float16* __restrict__ KPTh)
{
    __shared__ float As[32][68];   // [kk][m], padded

    const int t     = threadIdx.x;
    const int bid   = blockIdx.x;
    const bool modeK = bid >= 256;
    const int lb    = modeK ? bid - 256 : bid;
    const int ntile = lb & 7;
    const int mtile = lb >> 3;
    const int m0    = mtile * 64;
    const int n0    = ntile * 64;

    const float* X = modeK ? key : query;
    const float* W = modeK ? (W1 + (size_t)H_ * HM_) : W1;

    const int mq = modeK ? (t & 15) : (t >> 4);
    const int nq = modeK ? (t >> 4) : (t & 15);

    // staging coordinates
    const int cs = t & 7;    // k-quad within 32-wide K-slab
    const int rs = t >> 3;   // m-row (0..31), two passes 32 apart

    const float* xs0 = X + (size_t)(m0 + rs) * H_ + cs * 4;
    const float* xs1 = xs0 + (size_t)32 * H_;

    float4 xv0 = *(const float4*)xs0;
    float4 xv1 = *(const float4*)xs1;

    float4 acc[4];
#pragma unroll
    for (int i = 0; i < 4; ++i) acc[i] = make_float4(0.f, 0.f, 0.f, 0.f);

    const float* wbase = W + n0 + nq * 4;

    for (int step = 0; step < 8; ++step) {
        if (step > 0) __syncthreads();
        As[cs * 4 + 0][rs] = xv0.x;
        As[cs * 4 + 1][rs] = xv0.y;
        As[cs * 4 + 2][rs] = xv0.z;
        As[cs * 4 + 3][rs] = xv0.w;
        As[cs * 4 + 0][rs + 32] = xv1.x;
        As[cs * 4 + 1][rs + 32] = xv1.y;
        As[cs * 4 + 2][rs + 32] = xv1.z;
        As[cs * 4 + 3][rs + 32] = xv1.w;
        __syncthreads();

        if (step < 7) {
            xv0 = *(const float4*)(xs0 + (step + 1) * 32);
            xv1 = *(const float4*)(xs1 + (step + 1) * 32);
        }

        const float* wrow = wbase + (size_t)(step * 32) * HM_;
#pragma unroll 8
        for (int kk = 0; kk < 32; ++kk) {
            float4 a4 = *(const float4*)&As[kk][mq * 4];
            float4 bf = *(const float4*)(wrow + (size_t)kk * HM_);
            float s0, s1, s2, s3;
            float4 v;
            if (!modeK) { s0 = a4.x; s1 = a4.y; s2 = a4.z; s3 = a4.w; v = bf; }
            else        { s0 = bf.x; s1 = bf.y; s2 = bf.z; s3 = bf.w; v = a4; }
            acc[0].x = fmaf(s0, v.x, acc[0].x); acc[0].y = fmaf(s0, v.y, acc[0].y);
            acc[0].z = fmaf(s0, v.z, acc[0].z); acc[0].w = fmaf(s0, v.w, acc[0].w);
            acc[1].x = fmaf(s1, v.x, acc[1].x); acc[1].y = fmaf(s1, v.y, acc[1].y);
            acc[1].z = fmaf(s1, v.z, acc[1].z); acc[1].w = fmaf(s1, v.w, acc[1].w);
            acc[2].x = fmaf(s2, v.x, acc[2].x); acc[2].y = fmaf(s2, v.y, acc[2].y);
            acc[2].z = fmaf(s2, v.z, acc[2].z); acc[2].w = fmaf(s2, v.w, acc[2].w);
            acc[3].x = fmaf(s3, v.x, acc[3].x); acc[3].y = fmaf(s3, v.y, acc[3].y);
            acc[3].z = fmaf(s3, v.z, acc[3].z); acc[3].w = fmaf(s3, v.w, acc[3].w);
        }
    }

    if (!modeK) {
        // acc[i] = C[m0+mq*4+i][n0+nq*4 .. +3] -> fp16 natural store
#pragma unroll
        for (int i = 0; i < 4; ++i) {
            hf4 hv = { (_Float16)acc[i].x, (_Float16)acc[i].y,
                       (_Float16)acc[i].z, (_Float16)acc[i].w };
            *(hf4*)(QPh + (size_t)(m0 + mq * 4 + i) * HM_ + n0 + nq * 4) = hv;
        }
    } else {
        // acc[j] = C[m0+mq*4 .. +3][n0+nq*4+j]; add bias, transpose,
        // store fp16 into KPTh[b][h/8][k][8]
        float4 b4 = *(const float4*)(b1 + n0 + nq * 4);
        acc[0].x += b4.x; acc[0].y += b4.x; acc[0].z += b4.x; acc[0].w += b4.x;
        acc[1].x += b4.y; acc[1].y += b4.y; acc[1].z += b4.y; acc[1].w += b4.y;
        acc[2].x += b4.z; acc[2].y += b4.z; acc[2].z += b4.z; acc[2].w += b4.z;
        acc[3].x += b4.w; acc[3].y += b4.w; acc[3].z += b4.w; acc[3].w += b4.w;
        const int bb    = m0 >> 8;
        const int nbase = n0 + nq * 4;
        const int h8    = nbase >> 3;
        const int sub   = (nbase >> 2) & 1;
        const int mloc  = (m0 & 255) + mq * 4;
#pragma unroll
        for (int x = 0; x < 4; ++x) {
            // k-row = mloc + x, halves for n = nbase..nbase+3
            const float* a = (const float*)acc;
            hf4 hv = { (_Float16)a[0 * 4 + x], (_Float16)a[1 * 4 + x],
                       (_Float16)a[2 * 4 + x], (_Float16)a[3 * 4 + x] };
            _Float16* dst = KPTh +
                (((size_t)bb * 64 + h8) * 256 + mloc + x) * 8 + sub * 4;
            *(hf4*)dst = hv;
        }
    }
}

// ---------------------------------------------------------------------------
// attn: block = (b, 4 q-rows), 512 threads: k = t&255, hb = t>>8.
//  phase 1 (fp16): per 8-h chunk: kv = 16B coalesced global, qv/w4 = 16B LDS
//           broadcast; v_pk_add/v_pk_max/v_dot2 -> f32 acc.
//  phase 2: combine halves + b2, mask, exp (fp32).
//  phase 3: rowsum; PV 8-way distinct split-k (wave w owns 32 value rows,
//           all 4 q); LDS combine.
// ---------------------------------------------------------------------------
__global__ __launch_bounds__(512, 4) void attn_kernel(
    const _Float16* __restrict__ QPh,  // [B*S1][HM]
    const _Float16* __restrict__ KPTh, // [B][HM/8][S2][8] (b1 folded)
    const float* __restrict__ value,   // [B, S2, H]
    const float* __restrict__ q_mask,  // [B, S1]
    const float* __restrict__ k_mask,  // [B, S2]
    const float* __restrict__ W2,      // [HM]
    const float* __restrict__ b2,      // [1]
    float* __restrict__ out)           // [B, S1, H]
{
    __shared__ __align__(16) _Float16 qp_h[QB][HM_];   // 4 KB
    __shared__ __align__(16) _Float16 w2_h[HM_];       // 1 KB
    __shared__ __align__(16) float    Ap[2][QB][S2_];  // 8 KB
    __shared__ __align__(16) float4   opart[8][QB][64];// 32 KB
    __shared__ float rA_s[QB];
    __shared__ float qm_s[QB];
    __shared__ float km_s[S2_];

    const int t  = threadIdx.x;
    const int k  = t & 255;
    const int hb = t >> 8;

    // XCD-aware swizzle: 512 blocks, XCD x gets 64 consecutive wg = 2 b's
    const int orig = blockIdx.x + (int)gridDim.x * blockIdx.y;  // 0..511
    const int wg   = (orig & 7) * 64 + (orig >> 3);
    const int q0   = (wg & 31) * QB;
    const int b    = wg >> 5;

    // stage qp (fp16, 4 rows x 512 = 4 KB = 256 x uint4), w2 (cvt), masks
    {
        if (t < 256) {
            const uint4* src = (const uint4*)(QPh + (size_t)(b * S1_ + q0) * HM_);
            ((uint4*)&qp_h[0][0])[t] = src[t];
            km_s[t] = k_mask[b * S2_ + t];
        } else if (t < 256 + 128) {
            const int i = t - 256;
            float4 wv = ((const float4*)W2)[i];
            hf4 hv = { (_Float16)wv.x, (_Float16)wv.y,
                       (_Float16)wv.z, (_Float16)wv.w };
            *(hf4*)&w2_h[i * 4] = hv;
        } else if (t < 256 + 128 + QB) {
            const int i = t - (256 + 128);
            qm_s[i] = q_mask[b * S1_ + q0 + i];
        }
    }
    __syncthreads();

    // phase 1: score partials over this thread's h half (32 chunks of 8 h)
    float accs[QB] = {0.f, 0.f, 0.f, 0.f};
    const uint4* kp8 = (const uint4*)KPTh + ((size_t)b * 64 + hb * 32) * S2_ + k;

    for (int c = 0; c < 32; ++c) {
        uint4 kvu = kp8[(size_t)c * S2_];
        const int hoff = hb * (HM_ / 2) + c * 8;
        uint4 w4u = *(const uint4*)&w2_h[hoff];
        hf2 kv0 = u2h(kvu.x), kv1 = u2h(kvu.y), kv2 = u2h(kvu.z), kv3 = u2h(kvu.w);
        hf2 wv0 = u2h(w4u.x), wv1 = u2h(w4u.y), wv2 = u2h(w4u.z), wv3 = u2h(w4u.w);
        const hf2 zero = (hf2)(_Float16)0;
#pragma unroll
        for (int q = 0; q < QB; ++q) {
            uint4 qvu = *(const uint4*)&qp_h[q][hoff];
            hf2 s;
            s = __builtin_elementwise_max(u2h(qvu.x) + kv0, zero);
            accs[q] = dot2(s, wv0, accs[q]);
            s = __builtin_elementwise_max(u2h(qvu.y) + kv1, zero);
            accs[q] = dot2(s, wv1, accs[q]);
            s = __builtin_elementwise_max(u2h(qvu.z) + kv2, zero);
            accs[q] = dot2(s, wv2, accs[q]);
            s = __builtin_elementwise_max(u2h(qvu.w) + kv3, zero);
            accs[q] = dot2(s, wv3, accs[q]);
        }
    }
#pragma unroll
    for (int q = 0; q < QB; ++q) Ap[hb][q][k] = accs[q];
    __syncthreads();

    // phase 2: combine halves, mask, exp (in place into Ap[0])
    {
        const float b2v = b2[0];
#pragma unroll
        for (int i = 0; i < 2; ++i) {
            const int idx = t + i * 512;           // 0..1023
            const int q = idx >> 8, kk = idx & 255;
            float sc = Ap[0][q][kk] + Ap[1][q][kk] + b2v;
            Ap[0][q][kk] = (qm_s[q] * km_s[kk] == 0.f) ? 0.f : __expf(sc);
        }
    }
    __syncthreads();

    // row sums: waves 0..3 (one per q-row), 64-lane butterfly
    if (t < QB * 64) {
        const int q = t >> 6, lane = t & 63;
        float p = Ap[0][q][lane] + Ap[0][q][lane + 64] +
                  Ap[0][q][lane + 128] + Ap[0][q][lane + 192];
#pragma unroll
        for (int m = 32; m >= 1; m >>= 1) p += __shfl_xor(p, m, 64);
        if (lane == 0) rA_s[q] = 1.0f / fmaxf(p, 2e-15f);
    }
    __syncthreads();

    // PV: wave w owns value rows [w*32, w*32+32) for ALL 4 q (no redundancy)
    {
        const int w = t >> 6, lane = t & 63;
        const float4* vb = (const float4*)(value + (size_t)b * S2_ * H_)
                           + (size_t)(w * 32) * (H_ / 4) + lane;
        float4 o[QB];
#pragma unroll
        for (int q = 0; q < QB; ++q) o[q] = make_float4(0.f, 0.f, 0.f, 0.f);
#pragma unroll 4
        for (int kk = 0; kk < 32; ++kk) {
            float4 v = vb[(size_t)kk * (H_ / 4)];
#pragma unroll
            for (int q = 0; q < QB; ++q) {
                float a = Ap[0][q][w * 32 + kk];
                o[q].x = fmaf(a, v.x, o[q].x); o[q].y = fmaf(a, v.y, o[q].y);
                o[q].z = fmaf(a, v.z, o[q].z); o[q].w = fmaf(a, v.w, o[q].w);
            }
        }
#pragma unroll
        for (int q = 0; q < QB; ++q) opart[w][q][lane] = o[q];
    }
    __syncthreads();

    // combine 8 partials, normalize, store
    if (t < QB * 64) {
        const int q = t >> 6, lane = t & 63;
        float4 s = make_float4(0.f, 0.f, 0.f, 0.f);
#pragma unroll
        for (int w = 0; w < 8; ++w) {
            float4 p = opart[w][q][lane];
            s.x += p.x; s.y += p.y; s.z += p.z; s.w += p.w;
        }
        const float r = rA_s[q];
        s.x *= r; s.y *= r; s.z *= r; s.w *= r;
        *(float4*)(out + (size_t)(b * S1_ + q0 + q) * H_ + lane * 4) = s;
    }
}

extern "C" void kernel_launch(void* const* d_in, const int* in_sizes, int n_in,
                              void* d_out, int out_size, void* d_ws, size_t ws_size,
                              hipStream_t stream) {
    const float* query  = (const float*)d_in[0];  // [16,128,256]
    const float* key    = (const float*)d_in[1];  // [16,256,256]
    const float* value  = (const float*)d_in[2];  // [16,256,256]
    const float* q_mask = (const float*)d_in[3];  // [16,128]
    const float* k_mask = (const float*)d_in[4];  // [16,256]
    const float* W1     = (const float*)d_in[5];  // [512,512]
    const float* b1     = (const float*)d_in[6];  // [512]
    const float* W2     = (const float*)d_in[7];  // [512,1]
    const float* b2     = (const float*)d_in[8];  // [1]
    float*       out    = (float*)d_out;

    _Float16* QPh  = (_Float16*)d_ws;                        // 2 MB
    _Float16* KPTh = QPh + (size_t)B_ * S1_ * HM_;           // 4 MB

    // merged projections: blocks [0,256) -> QPh, [256,768) -> KPTh
    proj_all_kernel<<<768, 256, 0, stream>>>(query, key, W1, b1, QPh, KPTh);

    attn_kernel<<<dim3(S1_ / QB, B_), 512, 0, stream>>>(
        QPh, KPTh, value, q_mask, k_mask, W2, b2, out);
}

// Round 6
// 41.940 us; speedup vs baseline: 7.2838x; 1.9902x over previous
//
#include <hip/hip_runtime.h>
#include <hip/hip_bf16.h>

// Problem constants
#define B_  16
#define S1_ 128
#define S2_ 256
#define H_  256
#define HM_ 512
#define QB  4   // q-rows per attn block

typedef _Float16 hf2 __attribute__((ext_vector_type(2)));
typedef _Float16 hf4 __attribute__((ext_vector_type(4)));
typedef _Float16 hf8 __attribute__((ext_vector_type(8)));
typedef float    f32x4 __attribute__((ext_vector_type(4)));

static __device__ inline hf2 u2h(unsigned u) {
    union { unsigned u; hf2 h; } x; x.u = u; return x.h;
}

static __device__ inline float dot2(hf2 a, hf2 b, float c) {
#if __has_builtin(__builtin_amdgcn_fdot2)
    return __builtin_amdgcn_fdot2(a, b, c, false);
#else
    asm("v_dot2_f32_f16 %0, %1, %2, %0" : "+v"(c) : "v"(a), "v"(b));
    return c;
#endif
}

// ---------------------------------------------------------------------------
// cvtW: Wt[n][k] = fp16(W1[k][n]).  262144 elems, 1024 blocks x 256.
// Writes coalesced (adjacent u -> adjacent k); reads are strided dword
// gathers that L2-serve after first touch (W1 = 1 MB).
// ---------------------------------------------------------------------------
__global__ __launch_bounds__(256) void cvtW_kernel(
    const float* __restrict__ W1, _Float16* __restrict__ Wt)
{
    const int u = blockIdx.x * 256 + threadIdx.x;   // 0..262143
    const int n = u >> 9, k = u & 511;
    Wt[u] = (_Float16)W1[(size_t)k * HM_ + n];
}

// ---------------------------------------------------------------------------
// proj_mfma: one launch, 768 blocks, 256 threads (4 waves).
//   blocks [0,256):   QPh  = fp16( query @ W1[:256] )          [2048][512]
//   blocks [256,768): KPTh = fp16( key @ W1[256:] + b1 )  [b][h/8][k][8]
// 64x64 tile, K=256 in 8 steps of 32. mfma_f32_16x16x32_f16, fp32 acc.
// X staged fp32->fp16 into LDS; Wt staged fp16. Rows padded to 40 halves
// (80 B) so b128 reads/writes are conflict-free (20*r mod 32 covers all
// banks over 8 rows).
// ---------------------------------------------------------------------------
__global__ __launch_bounds__(256) void proj_mfma_kernel(
    const float* __restrict__ query,
    const float* __restrict__ key,
    const _Float16* __restrict__ Wt,   // [512 n][512 k]
    const float* __restrict__ b1,
    _Float16* __restrict__ QPh,        // [2048][512]
    _Float16* __restrict__ KPTh)       // [16][64][256][8]
{
    __shared__ _Float16 Xs[64][40];
    __shared__ _Float16 Ws[64][40];

    const int t   = threadIdx.x;
    const int bid = blockIdx.x;
    const bool modeK = bid >= 256;
    const int lb    = modeK ? bid - 256 : bid;
    const int mtile = lb >> 3, ntile = lb & 7;
    const int m0 = mtile * 64, n0 = ntile * 64;
    const float* X = modeK ? key : query;
    const int kw = modeK ? 256 : 0;

    // staging geometry: thread covers (row = t>>2, k-chunk of 8 = t&3)
    const int srow = t >> 2;
    const int schk = t & 3;

    const float*    xsrc = X  + (size_t)(m0 + srow) * H_  + schk * 8;
    const _Float16* wsrc = Wt + (size_t)(n0 + srow) * HM_ + kw + schk * 8;

    // prefetch step 0
    float4 xa = *(const float4*)xsrc;
    float4 xb = *(const float4*)(xsrc + 4);
    uint4  wv = *(const uint4*)wsrc;

    f32x4 acc[4] = {};

    const int lane = t & 63, wid = t >> 6;
    const int fr = lane & 15;            // fragment fast index
    const int fk = (lane >> 4) * 8;      // k sub-block base

    for (int s = 0; s < 8; ++s) {
        __syncthreads();                 // previous step's readers done
        hf8 xh = { (_Float16)xa.x, (_Float16)xa.y, (_Float16)xa.z, (_Float16)xa.w,
                   (_Float16)xb.x, (_Float16)xb.y, (_Float16)xb.z, (_Float16)xb.w };
        *(hf8*)&Xs[srow][schk * 8]  = xh;
        *(uint4*)&Ws[srow][schk * 8] = wv;
        __syncthreads();

        if (s < 7) {                     // issue next step's loads early
            xa = *(const float4*)(xsrc + (s + 1) * 32);
            xb = *(const float4*)(xsrc + (s + 1) * 32 + 4);
            wv = *(const uint4*)(wsrc + (s + 1) * 32);
        }

        hf8 a = *(const hf8*)&Xs[wid * 16 + fr][fk];
#pragma unroll
        for (int nf = 0; nf < 4; ++nf) {
            hf8 b = *(const hf8*)&Ws[nf * 16 + fr][fk];
            acc[nf] = __builtin_amdgcn_mfma_f32_16x16x32_f16(a, b, acc[nf], 0, 0, 0);
        }
    }

    // epilogue: D[row][col], col = lane&15 (n), row = (lane>>4)*4+reg (m)
    if (!modeK) {
#pragma unroll
        for (int nf = 0; nf < 4; ++nf) {
            const int n = n0 + nf * 16 + fr;
#pragma unroll
            for (int r = 0; r < 4; ++r) {
                const int m = m0 + wid * 16 + (lane >> 4) * 4 + r;
                QPh[(size_t)m * HM_ + n] = (_Float16)acc[nf][r];
            }
        }
    } else {
#pragma unroll
        for (int nf = 0; nf < 4; ++nf) {
            const int n = n0 + nf * 16 + fr;
            const float bv = b1[n];
#pragma unroll
            for (int r = 0; r < 4; ++r) {
                const int m    = m0 + wid * 16 + (lane >> 4) * 4 + r;  // key row
                const int bb   = m >> 8, kloc = m & 255;
                KPTh[(((size_t)bb * 64 + (n >> 3)) * 256 + kloc) * 8 + (n & 7)] =
                    (_Float16)(acc[nf][r] + bv);
            }
        }
    }
}

// ---------------------------------------------------------------------------
// attn: block = (b, 4 q-rows), 512 threads: k = t&255, hb = t>>8.
//  phase 1 (fp16): per 8-h chunk: kv = 16B coalesced global, qv/w4 = 16B LDS
//           broadcast; v_pk_add/v_pk_max/v_dot2 -> f32 acc.
//  phase 2: combine halves + b2, mask, exp (fp32).
//  phase 3: rowsum; PV 8-way distinct split-k; LDS combine.
// ---------------------------------------------------------------------------
__global__ __launch_bounds__(512, 4) void attn_kernel(
    const _Float16* __restrict__ QPh,  // [B*S1][HM]
    const _Float16* __restrict__ KPTh, // [B][HM/8][S2][8] (b1 folded)
    const float* __restrict__ value,   // [B, S2, H]
    const float* __restrict__ q_mask,  // [B, S1]
    const float* __restrict__ k_mask,  // [B, S2]
    const float* __restrict__ W2,      // [HM]
    const float* __restrict__ b2,      // [1]
    float* __restrict__ out)           // [B, S1, H]
{
    __shared__ __align__(16) _Float16 qp_h[QB][HM_];   // 4 KB
    __shared__ __align__(16) _Float16 w2_h[HM_];       // 1 KB
    __shared__ __align__(16) float    Ap[2][QB][S2_];  // 8 KB
    __shared__ __align__(16) float4   opart[8][QB][64];// 32 KB
    __shared__ float rA_s[QB];
    __shared__ float qm_s[QB];
    __shared__ float km_s[S2_];

    const int t  = threadIdx.x;
    const int k  = t & 255;
    const int hb = t >> 8;

    // XCD-aware swizzle: 512 blocks, XCD x gets 64 consecutive wg = 2 b's
    const int orig = blockIdx.x + (int)gridDim.x * blockIdx.y;  // 0..511
    const int wg   = (orig & 7) * 64 + (orig >> 3);
    const int q0   = (wg & 31) * QB;
    const int b    = wg >> 5;

    // stage qp (fp16), w2 (cvt), masks
    {
        if (t < 256) {
            const uint4* src = (const uint4*)(QPh + (size_t)(b * S1_ + q0) * HM_);
            ((uint4*)&qp_h[0][0])[t] = src[t];
            km_s[t] = k_mask[b * S2_ + t];
        } else if (t < 256 + 128) {
            const int i = t - 256;
            float4 wvv = ((const float4*)W2)[i];
            hf4 hv = { (_Float16)wvv.x, (_Float16)wvv.y,
                       (_Float16)wvv.z, (_Float16)wvv.w };
            *(hf4*)&w2_h[i * 4] = hv;
        } else if (t < 256 + 128 + QB) {
            const int i = t - (256 + 128);
            qm_s[i] = q_mask[b * S1_ + q0 + i];
        }
    }
    __syncthreads();

    // phase 1: score partials over this thread's h half (32 chunks of 8 h)
    float accs[QB] = {0.f, 0.f, 0.f, 0.f};
    const uint4* kp8 = (const uint4*)KPTh + ((size_t)b * 64 + hb * 32) * S2_ + k;

    for (int c = 0; c < 32; ++c) {
        uint4 kvu = kp8[(size_t)c * S2_];
        const int hoff = hb * (HM_ / 2) + c * 8;
        uint4 w4u = *(const uint4*)&w2_h[hoff];
        hf2 kv0 = u2h(kvu.x), kv1 = u2h(kvu.y), kv2 = u2h(kvu.z), kv3 = u2h(kvu.w);
        hf2 wv0 = u2h(w4u.x), wv1 = u2h(w4u.y), wv2 = u2h(w4u.z), wv3 = u2h(w4u.w);
        const hf2 zero = (hf2)(_Float16)0;
#pragma unroll
        for (int q = 0; q < QB; ++q) {
            uint4 qvu = *(const uint4*)&qp_h[q][hoff];
            hf2 s;
            s = __builtin_elementwise_max(u2h(qvu.x) + kv0, zero);
            accs[q] = dot2(s, wv0, accs[q]);
            s = __builtin_elementwise_max(u2h(qvu.y) + kv1, zero);
            accs[q] = dot2(s, wv1, accs[q]);
            s = __builtin_elementwise_max(u2h(qvu.z) + kv2, zero);
            accs[q] = dot2(s, wv2, accs[q]);
            s = __builtin_elementwise_max(u2h(qvu.w) + kv3, zero);
            accs[q] = dot2(s, wv3, accs[q]);
        }
    }
#pragma unroll
    for (int q = 0; q < QB; ++q) Ap[hb][q][k] = accs[q];
    __syncthreads();

    // phase 2: combine halves, mask, exp (in place into Ap[0])
    {
        const float b2v = b2[0];
#pragma unroll
        for (int i = 0; i < 2; ++i) {
            const int idx = t + i * 512;           // 0..1023
            const int q = idx >> 8, kk = idx & 255;
            float sc = Ap[0][q][kk] + Ap[1][q][kk] + b2v;
            Ap[0][q][kk] = (qm_s[q] * km_s[kk] == 0.f) ? 0.f : __expf(sc);
        }
    }
    __syncthreads();

    // row sums: waves 0..3 (one per q-row), 64-lane butterfly
    if (t < QB * 64) {
        const int q = t >> 6, lane = t & 63;
        float p = Ap[0][q][lane] + Ap[0][q][lane + 64] +
                  Ap[0][q][lane + 128] + Ap[0][q][lane + 192];
#pragma unroll
        for (int m = 32; m >= 1; m >>= 1) p += __shfl_xor(p, m, 64);
        if (lane == 0) rA_s[q] = 1.0f / fmaxf(p, 2e-15f);
    }
    __syncthreads();

    // PV: wave w owns value rows [w*32, w*32+32) for ALL 4 q (no redundancy)
    {
        const int w = t >> 6, lane = t & 63;
        const float4* vb = (const float4*)(value + (size_t)b * S2_ * H_)
                           + (size_t)(w * 32) * (H_ / 4) + lane;
        float4 o[QB];
#pragma unroll
        for (int q = 0; q < QB; ++q) o[q] = make_float4(0.f, 0.f, 0.f, 0.f);
#pragma unroll 4
        for (int kk = 0; kk < 32; ++kk) {
            float4 v = vb[(size_t)kk * (H_ / 4)];
#pragma unroll
            for (int q = 0; q < QB; ++q) {
                float a = Ap[0][q][w * 32 + kk];
                o[q].x = fmaf(a, v.x, o[q].x); o[q].y = fmaf(a, v.y, o[q].y);
                o[q].z = fmaf(a, v.z, o[q].z); o[q].w = fmaf(a, v.w, o[q].w);
            }
        }
#pragma unroll
        for (int q = 0; q < QB; ++q) opart[w][q][lane] = o[q];
    }
    __syncthreads();

    // combine 8 partials, normalize, store
    if (t < QB * 64) {
        const int q = t >> 6, lane = t & 63;
        float4 s = make_float4(0.f, 0.f, 0.f, 0.f);
#pragma unroll
        for (int w = 0; w < 8; ++w) {
            float4 p = opart[w][q][lane];
            s.x += p.x; s.y += p.y; s.z += p.z; s.w += p.w;
        }
        const float r = rA_s[q];
        s.x *= r; s.y *= r; s.z *= r; s.w *= r;
        *(float4*)(out + (size_t)(b * S1_ + q0 + q) * H_ + lane * 4) = s;
    }
}

extern "C" void kernel_launch(void* const* d_in, const int* in_sizes, int n_in,
                              void* d_out, int out_size, void* d_ws, size_t ws_size,
                              hipStream_t stream) {
    const float* query  = (const float*)d_in[0];  // [16,128,256]
    const float* key    = (const float*)d_in[1];  // [16,256,256]
    const float* value  = (const float*)d_in[2];  // [16,256,256]
    const float* q_mask = (const float*)d_in[3];  // [16,128]
    const float* k_mask = (const float*)d_in[4];  // [16,256]
    const float* W1     = (const float*)d_in[5];  // [512,512]
    const float* b1     = (const float*)d_in[6];  // [512]
    const float* W2     = (const float*)d_in[7];  // [512,1]
    const float* b2     = (const float*)d_in[8];  // [1]
    float*       out    = (float*)d_out;

    _Float16* QPh  = (_Float16*)d_ws;                  // [2048][512]   2 MB
    _Float16* KPTh = QPh  + (size_t)B_ * S1_ * HM_;    // [16][64][256][8] 4 MB
    _Float16* Wt   = KPTh + (size_t)B_ * S2_ * HM_;    // [512][512]  0.5 MB

    // Wt[n][k] = fp16(W1[k][n])
    cvtW_kernel<<<1024, 256, 0, stream>>>(W1, Wt);

    // merged MFMA projections: blocks [0,256) -> QPh, [256,768) -> KPTh
    proj_mfma_kernel<<<768, 256, 0, stream>>>(query, key, Wt, b1, QPh, KPTh);

    attn_kernel<<<dim3(S1_ / QB, B_), 512, 0, stream>>>(
        QPh, KPTh, value, q_mask, k_mask, W2, b2, out);
}